// Round 6
// baseline (239.957 us; speedup 1.0000x reference)
//
#include <hip/hip_runtime.h>

#define B_LEN 32
#define C_LEN 512
#define L_LEN 4096
#define H_LEN 8
#define WIN 9
#define PADW 4

#define K1_NS 8
#define K1_CPER (C_LEN / K1_NS) // 64

// ---------------- Kernel 0: repack W [H][C][9] -> Wt [C][H][9] ----------------
// Makes the per-channel weight block contiguous (72 floats) for scalar loads.
__global__ __launch_bounds__(256) void repack_w(
    const float* __restrict__ W, float* __restrict__ Wt)
{
  const int i = blockIdx.x * 256 + threadIdx.x; // over C*H*WIN = 36864
  if (i >= C_LEN * H_LEN * WIN) return;
  const int w = i % WIN;
  const int h = (i / WIN) % H_LEN;
  const int c = i / (WIN * H_LEN);
  Wt[i] = W[((size_t)h * C_LEN + c) * WIN + w];
}

// ---------------- Kernel 1: conv partial, direct-load, no LDS, no barriers ----
// grid (L/1024, B, K1_NS) = 1024 blocks, block 256 (4 waves), 4 blocks/CU.
// Thread t owns outputs l = bx*1024 + 4t .. +3; per channel it reads its
// 12-float window as 3 coalesced float4 loads (lanes overlap -> L1 absorbs
// the 3x). No __syncthreads anywhere: each wave runs a private
// load->FMA stream the compiler software-pipelines (576 FMA-issue cycles
// per channel hide the next channel's load latency).
__global__ __launch_bounds__(256, 4) void conv_direct(
    const float* __restrict__ x, const float* __restrict__ Wt,
    float* __restrict__ part)
{
  const int t = threadIdx.x;
  const int li = blockIdx.x * 1024 + 4 * t;
  const int b = blockIdx.y;
  const int cbase = blockIdx.z * K1_CPER;
  const float* xb = x + (size_t)b * C_LEN * L_LEN + li;

  float acc[H_LEN][4];
#pragma unroll
  for (int h = 0; h < H_LEN; ++h)
#pragma unroll
    for (int j = 0; j < 4; ++j) acc[h][j] = 0.f;

  const bool lok = (li >= 4);            // left float4 fully in-bounds
  const bool rok = (li + 7 < L_LEN);     // right float4 fully in-bounds
  const float4 z4 = make_float4(0.f, 0.f, 0.f, 0.f);

#pragma unroll 2
  for (int c = 0; c < K1_CPER; ++c) {
    const float* xc = xb + (size_t)(cbase + c) * L_LEN;
    const float4 a0 = lok ? *reinterpret_cast<const float4*>(xc - 4) : z4;
    const float4 a1 = *reinterpret_cast<const float4*>(xc);
    const float4 a2 = rok ? *reinterpret_cast<const float4*>(xc + 4) : z4;
    float xv[12];
    xv[0] = a0.x; xv[1] = a0.y; xv[2]  = a0.z; xv[3]  = a0.w;
    xv[4] = a1.x; xv[5] = a1.y; xv[6]  = a1.z; xv[7]  = a1.w;
    xv[8] = a2.x; xv[9] = a2.y; xv[10] = a2.z; xv[11] = a2.w;
    const float* Wc = Wt + (size_t)(cbase + c) * (H_LEN * WIN); // uniform, contiguous 72 floats
#pragma unroll
    for (int h = 0; h < H_LEN; ++h) {
#pragma unroll
      for (int w = 0; w < WIN; ++w) {
        const float wv = Wc[h * WIN + w]; // uniform -> SGPR
#pragma unroll
        for (int j = 0; j < 4; ++j)
          acc[h][j] = fmaf(xv[w + j], wv, acc[h][j]);
      }
    }
  }

  float* dst = part + ((size_t)blockIdx.z * B_LEN * H_LEN + (size_t)b * H_LEN) * L_LEN + li;
#pragma unroll
  for (int h = 0; h < H_LEN; ++h) {
    float4 v;
    v.x = acc[h][0]; v.y = acc[h][1]; v.z = acc[h][2]; v.w = acc[h][3];
    *reinterpret_cast<float4*>(dst + (size_t)h * L_LEN) = v;
  }
}

// ---------------- Kernel 2: sum partials + softmax over L ----------------
__global__ __launch_bounds__(256) void softmax_rows(
    const float* __restrict__ part, float* __restrict__ focus)
{
  __shared__ float red[256];
  const int r = blockIdx.x; // b*H + h
  const int t = threadIdx.x;
  const size_t PART = (size_t)B_LEN * H_LEN * L_LEN;
  float v[16];
#pragma unroll
  for (int k = 0; k < 4; ++k) {
    const int i4 = (t + 256 * k) * 4;
    float4 a = *reinterpret_cast<const float4*>(&part[(size_t)r * L_LEN + i4]);
    v[4 * k + 0] = a.x; v[4 * k + 1] = a.y; v[4 * k + 2] = a.z; v[4 * k + 3] = a.w;
  }
  for (int s = 1; s < K1_NS; ++s) {
#pragma unroll
    for (int k = 0; k < 4; ++k) {
      const int i4 = (t + 256 * k) * 4;
      float4 a = *reinterpret_cast<const float4*>(&part[(size_t)s * PART + (size_t)r * L_LEN + i4]);
      v[4 * k + 0] += a.x; v[4 * k + 1] += a.y; v[4 * k + 2] += a.z; v[4 * k + 3] += a.w;
    }
  }
  // bias b[h] is constant along L -> softmax-invariant -> skipped
  float m = v[0];
#pragma unroll
  for (int k = 1; k < 16; ++k) m = fmaxf(m, v[k]);
  red[t] = m;
  __syncthreads();
  for (int s = 128; s > 0; s >>= 1) {
    if (t < s) red[t] = fmaxf(red[t], red[t + s]);
    __syncthreads();
  }
  m = red[0];
  __syncthreads();
  float sum = 0.f;
#pragma unroll
  for (int k = 0; k < 16; ++k) { v[k] = __expf(v[k] - m); sum += v[k]; }
  red[t] = sum;
  __syncthreads();
  for (int s = 128; s > 0; s >>= 1) {
    if (t < s) red[t] += red[t + s];
    __syncthreads();
  }
  const float inv = 1.f / red[0];
#pragma unroll
  for (int k = 0; k < 4; ++k) {
    const int i4 = (t + 256 * k) * 4;
    float4 a;
    a.x = v[4 * k + 0] * inv; a.y = v[4 * k + 1] * inv;
    a.z = v[4 * k + 2] * inv; a.w = v[4 * k + 3] * inv;
    *reinterpret_cast<float4*>(&focus[(size_t)r * L_LEN + i4]) = a;
  }
}

// ---------------- Kernel 3a: partial pooled over an L-split ----------------
// grid (C/64, B, K3_NS), block 256 -> 1024 blocks (4/CU, 16 waves/CU).
#define K3_ST 68
#define K3_NS 4

__global__ __launch_bounds__(256) void pool_partial(
    const float* __restrict__ x, const float* __restrict__ focus,
    float* __restrict__ pool2)
{
  __shared__ float xs[64 * K3_ST];
  const int t = threadIdx.x;
  const int cl = t & 63;
  const int p = t >> 6;                              // h-group 0..3 (wave-uniform)
  const int pu = __builtin_amdgcn_readfirstlane(p);  // force SGPR for focus addressing
  const int b = blockIdx.y;
  const int c0 = blockIdx.x * 64;
  const int lbeg = blockIdx.z * (L_LEN / K3_NS);
  const float* f0 = focus + ((size_t)b * H_LEN + pu) * L_LEN;
  const float* f1 = f0 + 4 * (size_t)L_LEN;
  const float* xb = x + (size_t)b * C_LEN * L_LEN;
  const int srow = t >> 4;
  const int scol = (t & 15) * 4;
  float acc0 = 0.f, acc1 = 0.f;

  for (int l0 = lbeg; l0 < lbeg + L_LEN / K3_NS; l0 += 64) {
    __syncthreads();
#pragma unroll
    for (int pass = 0; pass < 4; ++pass) {
      const int c = srow + pass * 16;
      float4 v = *reinterpret_cast<const float4*>(&xb[(size_t)(c0 + c) * L_LEN + l0 + scol]);
      *reinterpret_cast<float4*>(&xs[c * K3_ST + scol]) = v;
    }
    __syncthreads();
#pragma unroll
    for (int l4 = 0; l4 < 16; ++l4) {
      const float4 xv = *reinterpret_cast<const float4*>(&xs[cl * K3_ST + 4 * l4]);
      const int li = l0 + 4 * l4;
      acc0 = fmaf(xv.x, f0[li + 0], acc0);
      acc0 = fmaf(xv.y, f0[li + 1], acc0);
      acc0 = fmaf(xv.z, f0[li + 2], acc0);
      acc0 = fmaf(xv.w, f0[li + 3], acc0);
      acc1 = fmaf(xv.x, f1[li + 0], acc1);
      acc1 = fmaf(xv.y, f1[li + 1], acc1);
      acc1 = fmaf(xv.z, f1[li + 2], acc1);
      acc1 = fmaf(xv.w, f1[li + 3], acc1);
    }
  }
  // partial pooled, layout [ls][b][c][h]
  float* dst = pool2 + (((size_t)blockIdx.z * B_LEN + b) * C_LEN + c0 + cl) * H_LEN;
  dst[p] = acc0;
  dst[p + 4] = acc1;
}

// ---------------- Kernel 3b: sum L-splits, max over heads ----------------
__global__ __launch_bounds__(256) void pool_reduce(
    const float* __restrict__ pool2, float* __restrict__ out)
{
  const int i = blockIdx.x * 256 + threadIdx.x; // over B*C
  float s[H_LEN];
#pragma unroll
  for (int h = 0; h < H_LEN; ++h) s[h] = 0.f;
  for (int ls = 0; ls < K3_NS; ++ls) {
    const float* src = pool2 + ((size_t)ls * B_LEN * C_LEN + i) * H_LEN;
    float4 a = *reinterpret_cast<const float4*>(src);
    float4 b4 = *reinterpret_cast<const float4*>(src + 4);
    s[0] += a.x; s[1] += a.y; s[2] += a.z; s[3] += a.w;
    s[4] += b4.x; s[5] += b4.y; s[6] += b4.z; s[7] += b4.w;
  }
  float m = s[0];
#pragma unroll
  for (int h = 1; h < H_LEN; ++h) m = fmaxf(m, s[h]);
  out[i] = m;
}

extern "C" void kernel_launch(void* const* d_in, const int* in_sizes, int n_in,
                              void* d_out, int out_size, void* d_ws, size_t ws_size,
                              hipStream_t stream)
{
  const float* x = (const float*)d_in[0];
  const float* W = (const float*)d_in[1];
  // d_in[2] = bias: constant along L, softmax-invariant -> no effect on output.
  float* out = (float*)d_out;
  float* ws = (float*)d_ws;

  const size_t PART = (size_t)B_LEN * H_LEN * L_LEN;            // 1M floats
  const size_t POOL2N = (size_t)K3_NS * B_LEN * C_LEN * H_LEN;  // 512K floats

  // ws layout (38.2 MB; R2/R5 confirmed ws_size covers the nsplit=8 layout):
  float* part = ws;                                  // 8 * 4 MB
  float* focus = ws + (size_t)K1_NS * PART;          // 4 MB
  float* pool2 = focus + PART;                       // 2 MB
  float* Wt = pool2 + POOL2N;                        // 144 KB

  hipLaunchKernelGGL(repack_w, dim3((C_LEN * H_LEN * WIN + 255) / 256), dim3(256), 0,
                     stream, W, Wt);
  hipLaunchKernelGGL(conv_direct, dim3(L_LEN / 1024, B_LEN, K1_NS), dim3(256), 0,
                     stream, x, Wt, part);
  hipLaunchKernelGGL(softmax_rows, dim3(B_LEN * H_LEN), dim3(256), 0,
                     stream, part, focus);
  hipLaunchKernelGGL(pool_partial, dim3(C_LEN / 64, B_LEN, K3_NS), dim3(256), 0,
                     stream, x, focus, pool2);
  hipLaunchKernelGGL(pool_reduce, dim3((B_LEN * C_LEN) / 256), dim3(256), 0,
                     stream, pool2, out);
}